// Round 1
// baseline (361.174 us; speedup 1.0000x reference)
//
#include <hip/hip_runtime.h>

#define NDIM 256
#define NC 129          // rfft output columns
#define NPAIRS 256

// W16[m] = exp(-2*pi*i*m/16): C16 = cos, S16 = -sin
__device__ constexpr float C16[16] = {
    1.0f,  0.9238795325112867f,  0.7071067811865476f,  0.3826834323650898f,
    0.0f, -0.3826834323650898f, -0.7071067811865476f, -0.9238795325112867f,
   -1.0f, -0.9238795325112867f, -0.7071067811865476f, -0.3826834323650898f,
    0.0f,  0.3826834323650898f,  0.7071067811865476f,  0.9238795325112867f };
__device__ constexpr float S16[16] = {
    0.0f, -0.3826834323650898f, -0.7071067811865476f, -0.9238795325112867f,
   -1.0f, -0.9238795325112867f, -0.7071067811865476f, -0.3826834323650898f,
    0.0f,  0.3826834323650898f,  0.7071067811865476f,  0.9238795325112867f,
    1.0f,  0.9238795325112867f,  0.7071067811865476f,  0.3826834323650898f };

// out[k] = sum_n (xr[n] + i*xi[n]) * W16^{n*k}
__device__ __forceinline__ void dft16(const float* xr, const float* xi,
                                      float* outr, float* outi) {
#pragma unroll
  for (int k = 0; k < 16; ++k) {
    float sr = 0.f, si = 0.f;
#pragma unroll
    for (int n = 0; n < 16; ++n) {
      const int m = (n * k) & 15;
      sr += xr[n] * C16[m] - xi[n] * S16[m];
      si += xr[n] * S16[m] + xi[n] * C16[m];
    }
    outr[k] = sr; outi[k] = si;
  }
}

__device__ __forceinline__ void dft16_real(const float* xr, float* outr, float* outi) {
#pragma unroll
  for (int k = 0; k < 16; ++k) {
    float sr = 0.f, si = 0.f;
#pragma unroll
    for (int n = 0; n < 16; ++n) {
      const int m = (n * k) & 15;
      sr += xr[n] * C16[m];
      si += xr[n] * S16[m];
    }
    outr[k] = sr; outi[k] = si;
  }
}

// ---------------- Stage 1: row-wise rfft (axis -1) per image -----------------
// block = one image (slot li); 256 threads; 16 row-groups of 16 rows.
__global__ __launch_bounds__(256) void stage1_kernel(
    const float* __restrict__ a, const float* __restrict__ b,
    float2* __restrict__ s1, int p0, int pc) {
  __shared__ float Bre[16 * 272];  // [lr]*272 + [n2]*17 + [k1]
  __shared__ float Bim[16 * 272];
  const int t = threadIdx.x;
  const int lr = t >> 4;
  const int sub = t & 15;
  const int li = blockIdx.x;
  const float* src = (li < pc) ? (a + (size_t)(p0 + li) * (NDIM * NDIM))
                               : (b + (size_t)(p0 + li - pc) * (NDIM * NDIM));
  float2* dst = s1 + (size_t)li * (NDIM * NC);

  // twiddle step W256^{sub} = exp(-2*pi*i*sub/256), double precision
  double sts, stc;
  sincos(-6.283185307179586 * (double)sub / 256.0, &sts, &stc);

  for (int g = 0; g < 16; ++g) {
    const int row = g * 16 + lr;
    // phase 1: this thread = (row, n2=sub): A[k1] = sum_n1 x[16*n1+n2] W16^{n1 k1}
    float xr[16];
    const float* xrow = src + row * NDIM + sub;
#pragma unroll
    for (int n1 = 0; n1 < 16; ++n1) xr[n1] = xrow[16 * n1];
    float ar[16], ai[16];
    dft16_real(xr, ar, ai);
    // twiddle by W256^{n2*k1}, store B
    double wr = 1.0, wi = 0.0;
#pragma unroll
    for (int k1 = 0; k1 < 16; ++k1) {
      const float fwr = (float)wr, fwi = (float)wi;
      Bre[lr * 272 + sub * 17 + k1] = ar[k1] * fwr - ai[k1] * fwi;
      Bim[lr * 272 + sub * 17 + k1] = ar[k1] * fwi + ai[k1] * fwr;
      const double nwr = wr * stc - wi * sts;
      wi = wr * sts + wi * stc; wr = nwr;
    }
    __syncthreads();
    // phase 2: this thread = (row, k1=sub): F[k1+16*k2] = sum_n2 B[n2][k1] W16^{n2 k2}
    float br[16], bi[16];
#pragma unroll
    for (int n2 = 0; n2 < 16; ++n2) {
      br[n2] = Bre[lr * 272 + n2 * 17 + sub];
      bi[n2] = Bim[lr * 272 + n2 * 17 + sub];
    }
    float fr[16], fi[16];
    dft16(br, bi, fr, fi);
    float2* drow = dst + row * NC;
#pragma unroll
    for (int k2 = 0; k2 < 16; ++k2) {
      const int k = sub + 16 * k2;
      if (k <= 128) drow[k] = make_float2(fr[k2], fi[k2]);
    }
    __syncthreads();
  }
}

// ------- Stage 2: column-wise 256-pt FFT + ring accumulation per pair --------
// block = (pair lp, column group g of 16 cols); 256 threads.
__global__ __launch_bounds__(256) void stage2_kernel(
    const float2* __restrict__ s1, const int* __restrict__ rr,
    float* __restrict__ partial, int p0, int pc) {
  __shared__ float Bre[16 * 272];
  __shared__ float Bim[16 * 272];
  __shared__ float2 FA[16 * 264];        // [col]*264 + [k0]
  __shared__ float binacc[4][3][132];    // per-wave bins
  const int t = threadIdx.x;
  const int col = t >> 4;
  const int sub = t & 15;
  const int wv = t >> 6;
  const int blk = blockIdx.x;
  const int lp = blk / 9;
  const int g = blk % 9;
  const int c0 = g * 16;
  const int W = (c0 + 16 <= NC) ? 16 : (NC - c0);
  const int cc = (c0 + col < NC) ? (c0 + col) : (NC - 1);
  const bool active = (col < W);

  for (int i = t; i < 4 * 3 * 132; i += 256) ((float*)binacc)[i] = 0.f;

  double sts, stc;
  sincos(-6.283185307179586 * (double)sub / 256.0, &sts, &stc);

  for (int im = 0; im < 2; ++im) {
    const float2* srcimg = s1 + (size_t)(lp + im * pc) * (NDIM * NC);
    // phase 1: thread (col, n2=sub): y[n1] = S1[16*n1+n2][cc]
    float yr[16], yi[16];
#pragma unroll
    for (int n1 = 0; n1 < 16; ++n1) {
      const float2 v = srcimg[(16 * n1 + sub) * NC + cc];
      yr[n1] = v.x; yi[n1] = v.y;
    }
    float ar[16], ai[16];
    dft16(yr, yi, ar, ai);
    double wr = 1.0, wi = 0.0;
#pragma unroll
    for (int k1 = 0; k1 < 16; ++k1) {
      const float fwr = (float)wr, fwi = (float)wi;
      Bre[col * 272 + sub * 17 + k1] = ar[k1] * fwr - ai[k1] * fwi;
      Bim[col * 272 + sub * 17 + k1] = ar[k1] * fwi + ai[k1] * fwr;
      const double nwr = wr * stc - wi * sts;
      wi = wr * sts + wi * stc; wr = nwr;
    }
    __syncthreads();
    // phase 2: thread (col, k1=sub): F2[k1+16*k2]
    float br[16], bi[16];
#pragma unroll
    for (int n2 = 0; n2 < 16; ++n2) {
      br[n2] = Bre[col * 272 + n2 * 17 + sub];
      bi[n2] = Bim[col * 272 + n2 * 17 + sub];
    }
    float fr[16], fi[16];
    dft16(br, bi, fr, fi);
    if (im == 0) {
#pragma unroll
      for (int k2 = 0; k2 < 16; ++k2) {
        const int k0 = sub + 16 * k2;
        FA[col * 264 + k0] = make_float2(fr[k2], fi[k2]);
      }
    } else if (active) {
#pragma unroll
      for (int k2 = 0; k2 < 16; ++k2) {
        const int k0 = sub + 16 * k2;
        const float2 fa = FA[col * 264 + k0];
        const float pa = fa.x * fa.x + fa.y * fa.y;
        const float pb = fr[k2] * fr[k2] + fi[k2] * fi[k2];
        const float nm = fa.x * fr[k2] + fa.y * fi[k2];
        const int bin = rr[k0 * NC + c0 + col];
        atomicAdd(&binacc[wv][0][bin], pa);
        atomicAdd(&binacc[wv][1][bin], pb);
        atomicAdd(&binacc[wv][2][bin], nm);
      }
    }
    __syncthreads();
  }
  // per-(pair, group) partial ring sums (deterministic layout, no global atomics)
  float* pdst = partial + (size_t)((p0 + lp) * 9 + g) * (3 * NC);
  for (int i = t; i < 3 * NC; i += 256) {
    const int q = i / NC, bin = i % NC;
    pdst[i] = binacc[0][q][bin] + binacc[1][q][bin] +
              binacc[2][q][bin] + binacc[3][q][bin];
  }
}

// ---------------- Stage 3a: per-pair FRC partial sum (double) ----------------
__global__ __launch_bounds__(128) void stage3a_kernel(
    const float* __restrict__ partial, double* __restrict__ pairsum) {
  const int pair = blockIdx.x;
  const int t = threadIdx.x;  // 128 threads; bins 1..126 active
  double v = 0.0;
  if (t >= 1 && t <= 126) {
    float na = 0.f, nb = 0.f, nm = 0.f;
    for (int g = 0; g < 9; ++g) {
      const float* p = partial + (size_t)(pair * 9 + g) * (3 * NC);
      na += p[t];
      nb += p[NC + t];
      nm += p[2 * NC + t];
    }
    const double den = fmax(sqrt((double)na) * sqrt((double)nb), 1e-4);
    v = (double)nm / den;
  }
  __shared__ double sd[128];
  sd[t] = v;
  __syncthreads();
  for (int s = 64; s > 0; s >>= 1) {
    if (t < s) sd[t] += sd[t + s];
    __syncthreads();
  }
  if (t == 0) pairsum[pair] = sd[0];
}

// ---------------- Stage 3b: final mean ---------------------------------------
__global__ __launch_bounds__(256) void stage3b_kernel(
    const double* __restrict__ pairsum, float* __restrict__ out) {
  const int t = threadIdx.x;
  __shared__ double sd[256];
  sd[t] = pairsum[t];
  __syncthreads();
  for (int s = 128; s > 0; s >>= 1) {
    if (t < s) sd[t] += sd[t + s];
    __syncthreads();
  }
  if (t == 0) out[0] = (float)(sd[0] / 32256.0);  // 256 pairs * 126 bins
}

extern "C" void kernel_launch(void* const* d_in, const int* in_sizes, int n_in,
                              void* d_out, int out_size, void* d_ws, size_t ws_size,
                              hipStream_t stream) {
  const float* a = (const float*)d_in[0];
  const float* b = (const float*)d_in[1];
  const int* rr = (const int*)d_in[2];
  float* out = (float*)d_out;

  char* ws = (char*)d_ws;
  const size_t partial_bytes = (size_t)NPAIRS * 9 * 3 * NC * sizeof(float);
  size_t off = (partial_bytes + 255) & ~(size_t)255;
  float* partial = (float*)ws;
  double* pairsum = (double*)(ws + off);
  off += ((size_t)NPAIRS * sizeof(double) + 255) & ~(size_t)255;
  float2* s1 = (float2*)(ws + off);

  const size_t bytes_per_img = (size_t)NDIM * NC * sizeof(float2);
  const size_t s1_avail = (ws_size > off) ? (ws_size - off) : 0;
  int cap = (int)(s1_avail / bytes_per_img);
  int P = cap / 2;
  if (P > NPAIRS) P = NPAIRS;
  if (P < 1) P = 1;  // assume workspace holds at least one pair

  for (int p0 = 0; p0 < NPAIRS; p0 += P) {
    const int pc = (NPAIRS - p0 < P) ? (NPAIRS - p0) : P;
    hipLaunchKernelGGL(stage1_kernel, dim3(2 * pc), dim3(256), 0, stream,
                       a, b, s1, p0, pc);
    hipLaunchKernelGGL(stage2_kernel, dim3(pc * 9), dim3(256), 0, stream,
                       s1, rr, partial, p0, pc);
  }
  hipLaunchKernelGGL(stage3a_kernel, dim3(NPAIRS), dim3(128), 0, stream,
                     partial, pairsum);
  hipLaunchKernelGGL(stage3b_kernel, dim3(1), dim3(256), 0, stream,
                     pairsum, out);
}